// Round 1
// baseline (278.131 us; speedup 1.0000x reference)
//
#include <hip/hip_runtime.h>

#define B_SZ 1024
#define H_SZ 2048
#define E_SZ 1024

typedef float  f32x4 __attribute__((ext_vector_type(4)));
typedef short  s16x8 __attribute__((ext_vector_type(8)));

__device__ __forceinline__ unsigned short f2bf(float f) {
    unsigned u = __float_as_uint(f);
    u = u + 0x7fffu + ((u >> 16) & 1u);   // RNE
    return (unsigned short)(u >> 16);
}
__device__ __forceinline__ float bf2f(unsigned short s) {
    return __uint_as_float(((unsigned)s) << 16);
}
__device__ __forceinline__ float sigm(float v) {
    return 1.0f / (1.0f + __expf(-v));
}

__device__ __forceinline__ void gll(const unsigned short* g, unsigned short* l) {
    __builtin_amdgcn_global_load_lds(
        (const __attribute__((address_space(1))) unsigned int*)g,
        (__attribute__((address_space(3))) unsigned int*)l, 16, 0, 0);
}

// ---------------------------------------------------------------- cast pass
struct CastArgs {
    const float*    src[11];
    unsigned short* dst[11];
    int             n[11];
};

__global__ __launch_bounds__(256) void cast_kernel(CastArgs a) {
    const int arr = blockIdx.y;
    const int n = a.n[arr];
    const float* __restrict__ s = a.src[arr];
    unsigned short* __restrict__ d = a.dst[arr];
    const int stride = gridDim.x * 256 * 4;
    for (int i = (blockIdx.x * 256 + threadIdx.x) * 4; i < n; i += stride) {
        float4 v = *(const float4*)(s + i);
        ushort4 o;
        o.x = f2bf(v.x); o.y = f2bf(v.y); o.z = f2bf(v.z); o.w = f2bf(v.w);
        *(ushort4*)(d + i) = o;
    }
}

// ----------------------------------------- bf16 GEMM core, BK=64 + swizzle
// (retained for the y split-K kernel)
__device__ __forceinline__ void gemm_accum64(
    const unsigned short* __restrict__ A,
    const unsigned short* __restrict__ W,
    int ld, int kLen, int m0, int n0,
    unsigned short* lA, unsigned short* lB,
    f32x4 acc[4][4], int t)
{
    const int lane = t & 63;
    const int w    = t >> 6;
    const int wr   = (w >> 1) << 6;
    const int wc   = (w & 1) << 6;
    const int lr   = lane & 15;
    const int q4   = lane >> 4;

    const int srow = t >> 3;
    const int scol = ((t & 7) ^ (srow & 7)) << 3;
    const unsigned short* gA = A + (size_t)(m0 + srow) * ld + scol;
    const unsigned short* gB = W + (size_t)(n0 + srow) * ld + scol;
    const size_t st32 = (size_t)32 * ld;

    const int cb0 = ((q4    ) ^ (lr & 7)) << 3;
    const int cb1 = ((4 + q4) ^ (lr & 7)) << 3;

    for (int k0 = 0; k0 < kLen; k0 += 64) {
#pragma unroll
        for (int p = 0; p < 4; ++p)
            gll(gA + k0 + p * st32, lA + (t + 256 * p) * 8);
#pragma unroll
        for (int p = 0; p < 4; ++p)
            gll(gB + k0 + p * st32, lB + (t + 256 * p) * 8);
        __syncthreads();

#pragma unroll
        for (int ks = 0; ks < 2; ++ks) {
            const int cb = ks ? cb1 : cb0;
            s16x8 af[4], bfr[4];
#pragma unroll
            for (int i = 0; i < 4; ++i)
                af[i] = *(const s16x8*)(lA + (wr + i * 16 + lr) * 64 + cb);
#pragma unroll
            for (int j = 0; j < 4; ++j)
                bfr[j] = *(const s16x8*)(lB + (wc + j * 16 + lr) * 64 + cb);
#pragma unroll
            for (int i = 0; i < 4; ++i)
#pragma unroll
                for (int j = 0; j < 4; ++j)
                    acc[i][j] = __builtin_amdgcn_mfma_f32_16x16x32_bf16(
                        af[i], bfr[j], acc[i][j], 0, 0, 0);
        }
        __syncthreads();
    }
}

// -------------------------------------------------------------- gate GEMMs
// 8-phase-style pipelined schedule (T2 swizzle + T3/T4 counted vmcnt + T5).
// BM=256 x BN=128 tiles over M=1024, N=4*2048 -> 256 blocks = 1/CU.
// 512 threads = 8 waves (4M x 2N), per-wave 64x64 output.
// LDS: A panels [buf2][kh2][256][32] bf16 (16KB ea), B [buf2][kh2][128][32]
// (8KB ea) = 96KB. Unified K: tiles 0..15 = E (X@Wx^T), 16..47 = H (H@Wh^T).
// Pipeline: per K-tile two phases (kh=0,1). Phase kh0 issues panels (t+1,kh1),
// phase kh1 issues (t+2,kh0); each phase ends vmcnt(6) (never 0 mid-loop):
// 9 gll peak in flight, waits leave the 6 newest outstanding.
#define GNT 48

__global__ __launch_bounds__(512, 2) void gates8_kernel(
    const unsigned short* __restrict__ Xb,
    const unsigned short* __restrict__ Hb,
    const unsigned short* __restrict__ Wxb,
    const unsigned short* __restrict__ Whb,
    const float* __restrict__ bi, const float* __restrict__ bg,
    const float* __restrict__ bff, const float* __restrict__ bo,
    unsigned short* __restrict__ Z)
{
    __shared__ unsigned short lA[4 * 8192];   // [buf][kh][256 rows][32 cols]
    __shared__ unsigned short lB[4 * 4096];   // [buf][kh][128 rows][32 cols]

    const int t   = threadIdx.x;
    const int b   = blockIdx.x;
    const int xcd = b & 7;
    const int i_  = b >> 3;                  // 0..31 within XCD
    const int ntg = xcd * 8 + (i_ >> 2);     // 0..63 gate-major col tile
    const int m0  = (i_ & 3) * 256;
    const int n0g = ntg * 128;
    const int q   = n0g >> 11;               // gate index
    const int nl  = n0g & (H_SZ - 1);        // col base within gate

    // staging: LDS linear chunk c -> (row=c>>2, pos=c&3); source chunk
    // pre-swizzled: pos ^ ((row>>1)&3)  (read side applies same XOR).
    const int sc = (((t & 3) ^ ((t >> 3) & 3)) << 3);   // src col (elems)
    const int rA = t >> 2;                               // 0..127
    const unsigned short* AE0 = Xb + (size_t)(m0 + rA) * E_SZ + sc;
    const unsigned short* AE1 = AE0 + (size_t)128 * E_SZ;
    const unsigned short* AH0 = Hb + (size_t)(m0 + rA) * H_SZ + sc;
    const unsigned short* AH1 = AH0 + (size_t)128 * H_SZ;
    const unsigned short* BEp = Wxb + (size_t)q * H_SZ * E_SZ + (size_t)(nl + rA) * E_SZ + sc;
    const unsigned short* BHp = Whb + (size_t)q * H_SZ * H_SZ + (size_t)(nl + rA) * H_SZ + sc;

    auto stageA = [&](int s, int kh) {   // 2 gll (16KB panel)
        unsigned short* d = lA + ((((s & 1) << 1) + kh) << 13) + t * 8;
        if (s < 16) { const int k = s * 64 + kh * 32;        gll(AE0 + k, d); gll(AE1 + k, d + 4096); }
        else        { const int k = (s - 16) * 64 + kh * 32; gll(AH0 + k, d); gll(AH1 + k, d + 4096); }
    };
    auto stageB = [&](int s, int kh) {   // 1 gll (8KB panel)
        unsigned short* d = lB + ((((s & 1) << 1) + kh) << 12) + t * 8;
        if (s < 16) gll(BEp + s * 64 + kh * 32, d);
        else        gll(BHp + (s - 16) * 64 + kh * 32, d);
    };

    // prologue: U(0,0), U(0,1), U(1,0) -> 9 gll in flight
    stageA(0, 0); stageB(0, 0);
    stageA(0, 1); stageB(0, 1);
    stageA(1, 0); stageB(1, 0);

    // fragment read offsets (swizzled), fixed per thread
    const int lane = t & 63;
    const int w    = t >> 6;
    const int wr   = (w >> 1) << 6;          // 0,64,128,192
    const int wc   = (w & 1) << 6;           // 0,64
    const int lr   = lane & 15;
    const int q4   = lane >> 4;
    int offA[4], offB[4];
#pragma unroll
    for (int i = 0; i < 4; ++i) {
        const int ra = wr + i * 16 + lr;
        offA[i] = ra * 32 + ((q4 ^ ((ra >> 1) & 3)) << 3);
        const int rb = wc + i * 16 + lr;
        offB[i] = rb * 32 + ((q4 ^ ((rb >> 1) & 3)) << 3);
    }

    f32x4 acc[4][4] = {};

    asm volatile("s_waitcnt vmcnt(6)" ::: "memory");   // U(0,0) done
    asm volatile("s_barrier" ::: "memory");

    for (int tt = 0; tt < GNT; ++tt) {
        const int bufb = (tt & 1) << 1;
        // ---------------- phase kh = 0 ----------------
        {
            const unsigned short* pA = lA + ((bufb + 0) << 13);
            const unsigned short* pB = lB + ((bufb + 0) << 12);
            s16x8 af[4], bv[4];
#pragma unroll
            for (int i = 0; i < 4; ++i) af[i] = *(const s16x8*)(pA + offA[i]);
#pragma unroll
            for (int j = 0; j < 4; ++j) bv[j] = *(const s16x8*)(pB + offB[j]);
            if (tt + 1 < GNT) { stageA(tt + 1, 1); stageB(tt + 1, 1); }
            asm volatile("s_barrier" ::: "memory");
            asm volatile("s_waitcnt lgkmcnt(0)" ::: "memory");
            __builtin_amdgcn_sched_barrier(0);
            __builtin_amdgcn_s_setprio(1);
#pragma unroll
            for (int i = 0; i < 4; ++i)
#pragma unroll
                for (int j = 0; j < 4; ++j)
                    acc[i][j] = __builtin_amdgcn_mfma_f32_16x16x32_bf16(
                        af[i], bv[j], acc[i][j], 0, 0, 0);
            __builtin_amdgcn_sched_barrier(0);
            __builtin_amdgcn_s_setprio(0);
            if (tt + 1 < GNT) asm volatile("s_waitcnt vmcnt(6)" ::: "memory"); // U(tt,1) done
            else              asm volatile("s_waitcnt vmcnt(0)" ::: "memory");
            asm volatile("s_barrier" ::: "memory");
        }
        // ---------------- phase kh = 1 ----------------
        {
            const unsigned short* pA = lA + ((bufb + 1) << 13);
            const unsigned short* pB = lB + ((bufb + 1) << 12);
            s16x8 af[4], bv[4];
#pragma unroll
            for (int i = 0; i < 4; ++i) af[i] = *(const s16x8*)(pA + offA[i]);
#pragma unroll
            for (int j = 0; j < 4; ++j) bv[j] = *(const s16x8*)(pB + offB[j]);
            if (tt + 2 < GNT) { stageA(tt + 2, 0); stageB(tt + 2, 0); }
            asm volatile("s_barrier" ::: "memory");
            asm volatile("s_waitcnt lgkmcnt(0)" ::: "memory");
            __builtin_amdgcn_sched_barrier(0);
            __builtin_amdgcn_s_setprio(1);
#pragma unroll
            for (int i = 0; i < 4; ++i)
#pragma unroll
                for (int j = 0; j < 4; ++j)
                    acc[i][j] = __builtin_amdgcn_mfma_f32_16x16x32_bf16(
                        af[i], bv[j], acc[i][j], 0, 0, 0);
            __builtin_amdgcn_sched_barrier(0);
            __builtin_amdgcn_s_setprio(0);
            if (tt + 2 < GNT)      asm volatile("s_waitcnt vmcnt(6)" ::: "memory"); // U(tt+1,0) done
            else if (tt + 1 < GNT) asm volatile("s_waitcnt vmcnt(3)" ::: "memory");
            asm volatile("s_barrier" ::: "memory");
        }
    }

    // epilogue: bias + activation, write bf16 Z
    const float* bias = (q == 0) ? bi : (q == 1) ? bg : (q == 2) ? bff : bo;
    unsigned short* Zq = Z + (size_t)q * B_SZ * H_SZ;
    const int rq = (lane >> 4) << 2;
#pragma unroll
    for (int i = 0; i < 4; ++i) {
#pragma unroll
        for (int j = 0; j < 4; ++j) {
            const int n = nl + wc + j * 16 + lr;
            const float bvv = bias[n];
#pragma unroll
            for (int r = 0; r < 4; ++r) {
                const int m = m0 + wr + i * 16 + rq + r;
                const float v = acc[i][j][r] + bvv;
                const float a = (q == 1) ? tanhf(v) : sigm(v);
                Zq[(size_t)m * H_SZ + n] = f2bf(a);
            }
        }
    }
}

// ------------------------------------------------------------ cell update
__global__ __launch_bounds__(256) void cell_kernel(
    const unsigned short* __restrict__ Z, const float* __restrict__ c,
    float* __restrict__ c_out, float* __restrict__ h_out,
    unsigned short* __restrict__ HnB)
{
    const size_t BH = (size_t)B_SZ * H_SZ;
    const int idx = (blockIdx.x * 256 + threadIdx.x) * 4;
    ushort4 iu = *(const ushort4*)(Z + idx);
    ushort4 gu = *(const ushort4*)(Z + BH + idx);
    ushort4 fu = *(const ushort4*)(Z + 2 * BH + idx);
    ushort4 ou = *(const ushort4*)(Z + 3 * BH + idx);
    float4 cv = *(const float4*)(c + idx);

    float cn[4], hn[4];
    cn[0] = bf2f(fu.x) * cv.x + bf2f(iu.x) * bf2f(gu.x);
    cn[1] = bf2f(fu.y) * cv.y + bf2f(iu.y) * bf2f(gu.y);
    cn[2] = bf2f(fu.z) * cv.z + bf2f(iu.z) * bf2f(gu.z);
    cn[3] = bf2f(fu.w) * cv.w + bf2f(iu.w) * bf2f(gu.w);
    hn[0] = bf2f(ou.x) * cn[0];
    hn[1] = bf2f(ou.y) * cn[1];
    hn[2] = bf2f(ou.z) * cn[2];
    hn[3] = bf2f(ou.w) * cn[3];

    *(float4*)(c_out + idx) = make_float4(cn[0], cn[1], cn[2], cn[3]);
    *(float4*)(h_out + idx) = make_float4(hn[0], hn[1], hn[2], hn[3]);
    ushort4 hb;
    hb.x = f2bf(hn[0]); hb.y = f2bf(hn[1]); hb.z = f2bf(hn[2]); hb.w = f2bf(hn[3]);
    *(ushort4*)(HnB + idx) = hb;
}

// ---------------------------------------------------- y GEMM, split-K by 4
__global__ __launch_bounds__(256) void y_split_kernel(
    const unsigned short* __restrict__ Hn,
    const unsigned short* __restrict__ Wy,
    float* __restrict__ part)
{
    __shared__ unsigned short lA[128 * 64];
    __shared__ unsigned short lB[128 * 64];
    const int t   = threadIdx.x;
    const int b   = blockIdx.x;
    const int xcd = b & 7;
    const int i_  = b >> 3;                 // 0..31 within XCD
    const int ns  = xcd * 4 + (i_ >> 3);    // 0..31: (n-tile, split)
    const int m0  = (i_ & 7) * 128;
    const int n0  = (ns >> 2) * 128;
    const int s   = ns & 3;

    f32x4 acc[4][4] = {};
    gemm_accum64(Hn + s * 512, Wy + s * 512, H_SZ, 512, m0, n0, lA, lB, acc, t);

    const int lane = t & 63, w = t >> 6;
    const int wr = (w >> 1) << 6, wc = (w & 1) << 6;
    const int lr = lane & 15, rq = (lane >> 4) << 2;
    float* P = part + (size_t)s * B_SZ * E_SZ;
#pragma unroll
    for (int i = 0; i < 4; ++i) {
#pragma unroll
        for (int j = 0; j < 4; ++j) {
            const int n = n0 + wc + j * 16 + lr;
#pragma unroll
            for (int r = 0; r < 4; ++r) {
                const int m = m0 + wr + i * 16 + rq + r;
                P[(size_t)m * E_SZ + n] = acc[i][j][r];
            }
        }
    }
}

__global__ __launch_bounds__(256) void y_reduce_kernel(
    const float* __restrict__ part, const float* __restrict__ by,
    float* __restrict__ yout)
{
    const size_t BE = (size_t)B_SZ * E_SZ;
    const int idx = (blockIdx.x * 256 + threadIdx.x) * 4;
    float4 a = *(const float4*)(part + idx);
    float4 b2 = *(const float4*)(part + BE + idx);
    float4 c2 = *(const float4*)(part + 2 * BE + idx);
    float4 d2 = *(const float4*)(part + 3 * BE + idx);
    const int col = idx & (E_SZ - 1);
    float4 bv = *(const float4*)(by + col);
    float4 o;
    o.x = tanhf(a.x + b2.x + c2.x + d2.x + bv.x);
    o.y = tanhf(a.y + b2.y + c2.y + d2.y + bv.y);
    o.z = tanhf(a.z + b2.z + c2.z + d2.z + bv.z);
    o.w = tanhf(a.w + b2.w + c2.w + d2.w + bv.w);
    *(float4*)(yout + idx) = o;
}

// ---------------------------------------------------------------- launch
extern "C" void kernel_launch(void* const* d_in, const int* in_sizes, int n_in,
                              void* d_out, int out_size, void* d_ws, size_t ws_size,
                              hipStream_t stream) {
    const float* x   = (const float*)d_in[0];
    const float* c   = (const float*)d_in[1];
    const float* h   = (const float*)d_in[2];
    const float* Wxi = (const float*)d_in[3];
    const float* Whi = (const float*)d_in[4];
    const float* Bi  = (const float*)d_in[5];
    const float* Wxg = (const float*)d_in[6];
    const float* Whg = (const float*)d_in[7];
    const float* Bg  = (const float*)d_in[8];
    const float* Wxf = (const float*)d_in[9];
    const float* Whf = (const float*)d_in[10];
    const float* Bf  = (const float*)d_in[11];
    const float* Wxo = (const float*)d_in[12];
    const float* Who = (const float*)d_in[13];
    const float* Bo  = (const float*)d_in[14];
    const float* Why = (const float*)d_in[15];
    const float* By  = (const float*)d_in[16];

    const size_t BE = (size_t)B_SZ * E_SZ, BH = (size_t)B_SZ * H_SZ;
    const size_t HE = (size_t)H_SZ * E_SZ, HH = (size_t)H_SZ * H_SZ;
    const size_t EH = (size_t)E_SZ * H_SZ;

    unsigned short* ws   = (unsigned short*)d_ws;
    unsigned short* Xb   = ws;                 // BE
    unsigned short* Hb   = Xb + BE;            // BH
    unsigned short* Wxb  = Hb + BH;            // 4*HE
    unsigned short* Whb  = Wxb + 4 * HE;       // 4*HH
    unsigned short* Whyb = Whb + 4 * HH;       // EH
    unsigned short* Z    = Whyb + EH;          // 4*BH bf16; later fp32 y-partials
    unsigned short* HnB  = Z + 4 * BH;         // BH

    CastArgs ca;
    ca.src[0]  = x;   ca.dst[0]  = Xb;           ca.n[0]  = (int)BE;
    ca.src[1]  = h;   ca.dst[1]  = Hb;           ca.n[1]  = (int)BH;
    ca.src[2]  = Wxi; ca.dst[2]  = Wxb;          ca.n[2]  = (int)HE;
    ca.src[3]  = Wxg; ca.dst[3]  = Wxb + HE;     ca.n[3]  = (int)HE;
    ca.src[4]  = Wxf; ca.dst[4]  = Wxb + 2 * HE; ca.n[4]  = (int)HE;
    ca.src[5]  = Wxo; ca.dst[5]  = Wxb + 3 * HE; ca.n[5]  = (int)HE;
    ca.src[6]  = Whi; ca.dst[6]  = Whb;          ca.n[6]  = (int)HH;
    ca.src[7]  = Whg; ca.dst[7]  = Whb + HH;     ca.n[7]  = (int)HH;
    ca.src[8]  = Whf; ca.dst[8]  = Whb + 2 * HH; ca.n[8]  = (int)HH;
    ca.src[9]  = Who; ca.dst[9]  = Whb + 3 * HH; ca.n[9]  = (int)HH;
    ca.src[10] = Why; ca.dst[10] = Whyb;         ca.n[10] = (int)EH;

    hipLaunchKernelGGL(cast_kernel, dim3(1024, 11), dim3(256), 0, stream, ca);
    hipLaunchKernelGGL(gates8_kernel, dim3(256), dim3(512), 0, stream,
                       Xb, Hb, Wxb, Whb, Bi, Bg, Bf, Bo, Z);

    float* y_out = (float*)d_out;
    float* c_out = y_out + BE;
    float* h_out = c_out + BH;
    hipLaunchKernelGGL(cell_kernel, dim3((unsigned)(BH / 1024)), dim3(256), 0, stream,
                       Z, c, c_out, h_out, HnB);

    float* ypart = (float*)Z;   // Z dead after cell_kernel
    hipLaunchKernelGGL(y_split_kernel, dim3(256), dim3(256), 0, stream,
                       HnB, Whyb, ypart);
    hipLaunchKernelGGL(y_reduce_kernel, dim3((unsigned)(BE / 1024)), dim3(256), 0, stream,
                       ypart, By, y_out);
}